// Round 1
// baseline (526.923 us; speedup 1.0000x reference)
//
#include <hip/hip_runtime.h>

#define EPS 1e-5f

constexpr int NN = 50000, NE = 800000, DD = 128, NG = 512, NC = 5, NO = 96;

// workspace float offsets
constexpr size_t AGG  = 0;                       // [NN*DD] agg, later reused as h (in place)
constexpr size_t CSUM = (size_t)NN * DD;         // [DD]
constexpr size_t CSQ  = CSUM + DD;               // [DD]
constexpr size_t POOL = CSQ + DD;                // [NG*DD]
constexpr size_t WRT  = POOL + (size_t)NG * DD;  // [DD*DD] transposed (k-major)
constexpr size_t WTT  = WRT + (size_t)DD * DD;   // [DD*DD]
constexpr size_t BRO  = WTT + (size_t)DD * DD;   // [DD]
constexpr size_t SCL  = BRO + DD;                // [DD]
constexpr size_t SHF  = SCL + DD;                // [DD]

// ---- fold the 5 convs' weights (sum commutes with the linears); store W^T k-major
__global__ void k_fold(const float* __restrict__ Wrel, const float* __restrict__ brel,
                       const float* __restrict__ Wroot, float* __restrict__ ws) {
    int o = threadIdx.x, k = blockIdx.x;
    float wr = 0.f, wt = 0.f;
    for (int c = 0; c < NC; ++c) {
        wr += Wrel [c*DD*DD + o*DD + k];
        wt += Wroot[c*DD*DD + o*DD + k];
    }
    ws[WRT + (size_t)k*DD + o] = wr;
    ws[WTT + (size_t)k*DD + o] = wt;
    if (k == 0) {
        float b = 0.f;
        for (int c = 0; c < NC; ++c) b += brel[c*DD + o];
        ws[BRO + o] = b;
    }
}

// ---- agg[dst] += x[src] over 800K edges (2 edges per 256-thread block)
__global__ void k_scatter(const float* __restrict__ x, const int* __restrict__ ei,
                          float* __restrict__ ws) {
    int e = blockIdx.x * 2 + (threadIdx.x >> 7);
    int d = threadIdx.x & 127;
    int src = ei[e];
    int dst = ei[NE + e];
    atomicAdd(&ws[AGG + (size_t)dst*DD + d], x[(size_t)src*DD + d]);
}

// ---- h = agg @ Wr^T + x @ Wt^T + br, written in place over agg; fused BN column sums
__global__ __launch_bounds__(256) void k_gemm(const float* __restrict__ x, float* __restrict__ ws) {
    __shared__ float aS[16][36];    // [k][row], pad 36: write bank = (4kk+r)%32 -> 2-way max
    __shared__ float wS[16][132];   // [k][col], pad 132 keeps float4 alignment
    __shared__ float red[8][128];
    const float* agg = ws + AGG;
    const float* wrt = ws + WRT;
    const float* wtt = ws + WTT;
    const float* br  = ws + BRO;
    int tid  = threadIdx.x;
    int row0 = blockIdx.x * 32;
    int c4 = (tid & 31) * 4;   // output col group
    int rg = tid >> 5;         // 0..7
    int r4 = rg * 4;           // row group within tile
    float acc[4][4] = {};
    for (int kc = 0; kc < 16; ++kc) {
        int k0 = kc * 16;
        const float* A = (k0 < 128) ? agg : x;
        const float* W = (k0 < 128) ? wrt : wtt;
        int kb = k0 & 127;
        #pragma unroll
        for (int i = 0; i < 2; ++i) {            // stage A tile: 32 rows x 16 k
            int idx = tid + i*256;
            int r = idx >> 4, kk = idx & 15;
            int gr = row0 + r; if (gr > NN-1) gr = NN-1;   // clamp; masked at epilogue
            aS[kk][r] = A[(size_t)gr*DD + kb + kk];
        }
        #pragma unroll
        for (int i = 0; i < 8; ++i) {            // stage W tile: 16 k x 128 cols
            int idx = tid + i*256;
            int kk = idx >> 7, o = idx & 127;
            wS[kk][o] = W[(size_t)(kb + kk)*DD + o];
        }
        __syncthreads();
        #pragma unroll
        for (int kk = 0; kk < 16; ++kk) {
            float4 a = *(const float4*)&aS[kk][r4];   // broadcast across col threads
            float4 w = *(const float4*)&wS[kk][c4];
            float av[4] = {a.x, a.y, a.z, a.w};
            float wv[4] = {w.x, w.y, w.z, w.w};
            #pragma unroll
            for (int i2 = 0; i2 < 4; ++i2)
                #pragma unroll
                for (int j = 0; j < 4; ++j)
                    acc[i2][j] += av[i2] * wv[j];
        }
        __syncthreads();
    }
    // epilogue: add bias, write h (in place over agg), accumulate BN sums
    float bv[4];
    #pragma unroll
    for (int j = 0; j < 4; ++j) bv[j] = br[c4 + j];
    float colp[4] = {}, sqp[4] = {};
    #pragma unroll
    for (int i = 0; i < 4; ++i) {
        int row = row0 + r4 + i;
        bool valid = row < NN;
        #pragma unroll
        for (int j = 0; j < 4; ++j) {
            float v = acc[i][j] + bv[j];
            if (valid) {
                ws[AGG + (size_t)row*DD + c4 + j] = v;
                colp[j] += v;
                sqp[j]  += v * v;
            }
        }
    }
    #pragma unroll
    for (int j = 0; j < 4; ++j) red[rg][c4 + j] = colp[j];
    __syncthreads();
    if (tid < 128) {
        float s = 0.f;
        #pragma unroll
        for (int g = 0; g < 8; ++g) s += red[g][tid];
        atomicAdd(&ws[CSUM + tid], s);
    }
    __syncthreads();
    #pragma unroll
    for (int j = 0; j < 4; ++j) red[rg][c4 + j] = sqp[j];
    __syncthreads();
    if (tid < 128) {
        float s = 0.f;
        #pragma unroll
        for (int g = 0; g < 8; ++g) s += red[g][tid];
        atomicAdd(&ws[CSQ + tid], s);
    }
}

// ---- BN affine folding: scale = gamma*rsqrt(var+eps), shift = beta - scale*mean
__global__ void k_stats(const float* __restrict__ gamma, const float* __restrict__ beta,
                        float* __restrict__ ws) {
    int o = threadIdx.x;
    float mean = ws[CSUM + o] * (1.0f / NN);
    float var  = ws[CSQ + o] * (1.0f / NN) - mean * mean;
    float inv  = rsqrtf(var + EPS);
    float sc   = gamma[o] * inv;
    ws[SCL + o] = sc;
    ws[SHF + o] = beta[o] - sc * mean;
}

// ---- normalize + relu + segment-max (batch sorted -> running max, flush on change)
__global__ void k_pool(const int* __restrict__ batch, float* __restrict__ ws) {
    int d  = threadIdx.x;
    int n0 = blockIdx.x * 64;
    int n1 = n0 + 64; if (n1 > NN) n1 = NN;
    float sc = ws[SCL + d], sh = ws[SHF + d];
    int cur = -1;
    float m = 0.f;   // relu(max(S)) == max over relu'd values with identity 0
    for (int n = n0; n < n1; ++n) {
        int g = batch[n];                  // wave-uniform
        if (g != cur) {
            if (cur >= 0)
                atomicMax((int*)&ws[POOL + (size_t)cur*DD + d], __float_as_int(m));
            cur = g; m = 0.f;
        }
        float v = ws[AGG + (size_t)n*DD + d] * sc + sh;
        m = fmaxf(m, fmaxf(v, 0.f));
    }
    if (cur >= 0)
        atomicMax((int*)&ws[POOL + (size_t)cur*DD + d], __float_as_int(m));
}

// ---- classifier: out[g] = relu_pooled[g] @ Wc^T + bc
__global__ void k_cls(const float* __restrict__ Wc, const float* __restrict__ bc,
                      const float* __restrict__ ws, float* __restrict__ out) {
    __shared__ float pS[128];
    int g = blockIdx.x, t = threadIdx.x;
    pS[t] = ws[POOL + (size_t)g*DD + t];
    __syncthreads();
    if (t < NO) {
        float acc = bc[t];
        #pragma unroll 8
        for (int k = 0; k < DD; ++k) acc += pS[k] * Wc[t*DD + k];
        out[g*NO + t] = acc;
    }
}

extern "C" void kernel_launch(void* const* d_in, const int* in_sizes, int n_in,
                              void* d_out, int out_size, void* d_ws, size_t ws_size,
                              hipStream_t stream) {
    const float* x     = (const float*)d_in[0];
    const int*   ei    = (const int*)  d_in[1];
    const int*   batch = (const int*)  d_in[2];
    // d_in[3] is i==0 -> no-dropout branch; unused
    const float* Wrel  = (const float*)d_in[4];
    const float* brel  = (const float*)d_in[5];
    const float* Wroot = (const float*)d_in[6];
    const float* gamma = (const float*)d_in[7];
    const float* beta  = (const float*)d_in[8];
    const float* Wc    = (const float*)d_in[9];
    const float* bc    = (const float*)d_in[10];
    float* ws  = (float*)d_ws;
    float* out = (float*)d_out;

    // zero agg + colsum + colsumsq + pooled in one contiguous memset
    size_t zeroFloats = POOL + (size_t)NG * DD;
    hipMemsetAsync(ws, 0, zeroFloats * sizeof(float), stream);

    k_fold   <<<DD, DD, 0, stream>>>(Wrel, brel, Wroot, ws);
    k_scatter<<<NE/2, 256, 0, stream>>>(x, ei, ws);
    k_gemm   <<<(NN + 31)/32, 256, 0, stream>>>(x, ws);
    k_stats  <<<1, DD, 0, stream>>>(gamma, beta, ws);
    k_pool   <<<(NN + 63)/64, DD, 0, stream>>>(batch, ws);
    k_cls    <<<NG, DD, 0, stream>>>(Wc, bc, ws, out);
}

// Round 2
// 327.115 us; speedup vs baseline: 1.6108x; 1.6108x over previous
//
#include <hip/hip_runtime.h>

#define EPS 1e-5f

constexpr int NN = 50000, NE = 800000, DD = 128, NG = 512, NC = 5, NO = 96;

// ---- workspace layout (float units for the float section) ----
constexpr size_t AGG  = 0;                       // [NN*DD] agg, later reused as h (in place)
constexpr size_t CSUM = (size_t)NN * DD;         // [DD]
constexpr size_t CSQ  = CSUM + DD;               // [DD]
constexpr size_t POOL = CSQ + DD;                // [NG*DD]
constexpr size_t WRT  = POOL + (size_t)NG * DD;  // [DD*DD] transposed (k-major)
constexpr size_t WTT  = WRT + (size_t)DD * DD;   // [DD*DD]
constexpr size_t BRO  = WTT + (size_t)DD * DD;   // [DD]
constexpr size_t SCL  = BRO + DD;                // [DD]
constexpr size_t SHF  = SCL + DD;                // [DD]
constexpr size_t F_END = SHF + DD;
// int section (offsets in int units, starting at F_END*4 bytes)
constexpr size_t CNT  = F_END;                   // [NN]   histogram, consumed by fill (atomicSub)
constexpr size_t ROFF = CNT + NN;                // [NN+1] CSR row offsets
constexpr size_t BSX  = ROFF + NN + 1;           // [256]  exclusive block sums
constexpr size_t CSR  = BSX + 256;               // [NE]   src indices grouped by dst

// ---- fold the 5 convs' weights (sum commutes with the linears); store W^T k-major
__global__ void k_fold(const float* __restrict__ Wrel, const float* __restrict__ brel,
                       const float* __restrict__ Wroot, float* __restrict__ ws) {
    int o = threadIdx.x, k = blockIdx.x;
    float wr = 0.f, wt = 0.f;
    for (int c = 0; c < NC; ++c) {
        wr += Wrel [c*DD*DD + o*DD + k];
        wt += Wroot[c*DD*DD + o*DD + k];
    }
    ws[WRT + (size_t)k*DD + o] = wr;
    ws[WTT + (size_t)k*DD + o] = wt;
    if (k == 0) {
        float b = 0.f;
        for (int c = 0; c < NC; ++c) b += brel[c*DD + o];
        ws[BRO + o] = b;
    }
}

// ---- CSR build: histogram of dst
__global__ void k_hist(const int* __restrict__ ei, int* __restrict__ wi) {
    int e = blockIdx.x * 256 + threadIdx.x;
    if (e < NE) atomicAdd(&wi[CNT + ei[NE + e]], 1);
}

// ---- scan step 1: per-block (256) sums of counts
__global__ void k_scan1(const int* __restrict__ wi, int* __restrict__ bsum) {
    __shared__ int s[256];
    int t = threadIdx.x, i = blockIdx.x * 256 + t;
    s[t] = (i < NN) ? wi[CNT + i] : 0;
    __syncthreads();
    for (int off = 128; off > 0; off >>= 1) {
        if (t < off) s[t] += s[t + off];
        __syncthreads();
    }
    if (t == 0) bsum[blockIdx.x] = s[0];
}

// ---- scan step 2: exclusive scan of the (<=256) block sums, in place -> BSX
__global__ void k_scan2(int* __restrict__ wi, const int* __restrict__ bsum, int nb) {
    __shared__ int s[256];
    int t = threadIdx.x;
    int v = (t < nb) ? bsum[t] : 0;
    s[t] = v;
    __syncthreads();
    for (int off = 1; off < 256; off <<= 1) {
        int u = (t >= off) ? s[t - off] : 0;
        __syncthreads();
        s[t] += u;
        __syncthreads();
    }
    wi[BSX + t] = s[t] - v;   // exclusive
}

// ---- scan step 3: block-local exclusive scan + block offset -> ROFF
__global__ void k_scan3(int* __restrict__ wi) {
    __shared__ int s[256];
    int t = threadIdx.x, b = blockIdx.x, i = b * 256 + t;
    int v = (i < NN) ? wi[CNT + i] : 0;
    s[t] = v;
    __syncthreads();
    for (int off = 1; off < 256; off <<= 1) {
        int u = (t >= off) ? s[t - off] : 0;
        __syncthreads();
        s[t] += u;
        __syncthreads();
    }
    if (i < NN) wi[ROFF + i] = wi[BSX + b] + s[t] - v;
    if (b == 0 && t == 0) wi[ROFF + NN] = NE;
}

// ---- fill CSR: consume CNT via atomicSub for slot positions
__global__ void k_fill(const int* __restrict__ ei, int* __restrict__ wi) {
    int e = blockIdx.x * 256 + threadIdx.x;
    if (e >= NE) return;
    int src = ei[e];
    int dst = ei[NE + e];
    int p = atomicSub(&wi[CNT + dst], 1) - 1;
    wi[CSR + wi[ROFF + dst] + p] = src;
}

// ---- gather-sum: agg[n] = sum_{e in row n} x[csr[e]]  (no atomics, streaming write)
__global__ __launch_bounds__(256) void k_gather(const float* __restrict__ x,
                                                const int* __restrict__ wi,
                                                float* __restrict__ ws) {
    int tid  = threadIdx.x;
    int n    = blockIdx.x * 8 + (tid >> 5);     // 8 nodes per block, 32 lanes per node
    int lane = tid & 31;
    int c4   = lane * 4;                        // 4 dims per lane (float4)
    if (n >= NN) return;
    int e0 = wi[ROFF + n], e1 = wi[ROFF + n + 1];
    int cnt = e1 - e0;
    float4 acc = {0.f, 0.f, 0.f, 0.f};
    for (int base = 0; base < cnt; base += 32) {
        int myE = (base + lane < cnt) ? wi[CSR + e0 + base + lane] : 0;  // coalesced
        int m = cnt - base; if (m > 32) m = 32;
        for (int j = 0; j < m; ++j) {
            int s = __shfl(myE, j, 32);         // broadcast within this node's 32-lane group
            float4 v = *(const float4*)&x[(size_t)s * DD + c4];
            acc.x += v.x; acc.y += v.y; acc.z += v.z; acc.w += v.w;
        }
    }
    *(float4*)&ws[AGG + (size_t)n * DD + c4] = acc;
}

// ---- h = agg @ Wr^T + x @ Wt^T + br, written in place over agg; fused BN column sums
__global__ __launch_bounds__(256) void k_gemm(const float* __restrict__ x, float* __restrict__ ws) {
    __shared__ float aS[16][36];    // [k][row], pad 36: write bank = (4kk+r)%32 -> 2-way max
    __shared__ float wS[16][132];   // [k][col], pad 132 keeps float4 alignment
    __shared__ float red[8][128];
    const float* agg = ws + AGG;
    const float* wrt = ws + WRT;
    const float* wtt = ws + WTT;
    const float* br  = ws + BRO;
    int tid  = threadIdx.x;
    int row0 = blockIdx.x * 32;
    int c4 = (tid & 31) * 4;   // output col group
    int rg = tid >> 5;         // 0..7
    int r4 = rg * 4;           // row group within tile
    float acc[4][4] = {};
    for (int kc = 0; kc < 16; ++kc) {
        int k0 = kc * 16;
        const float* A = (k0 < 128) ? agg : x;
        const float* W = (k0 < 128) ? wrt : wtt;
        int kb = k0 & 127;
        #pragma unroll
        for (int i = 0; i < 2; ++i) {            // stage A tile: 32 rows x 16 k
            int idx = tid + i*256;
            int r = idx >> 4, kk = idx & 15;
            int gr = row0 + r; if (gr > NN-1) gr = NN-1;   // clamp; masked at epilogue
            aS[kk][r] = A[(size_t)gr*DD + kb + kk];
        }
        #pragma unroll
        for (int i = 0; i < 8; ++i) {            // stage W tile: 16 k x 128 cols
            int idx = tid + i*256;
            int kk = idx >> 7, o = idx & 127;
            wS[kk][o] = W[(size_t)(kb + kk)*DD + o];
        }
        __syncthreads();
        #pragma unroll
        for (int kk = 0; kk < 16; ++kk) {
            float4 a = *(const float4*)&aS[kk][r4];   // broadcast across col threads
            float4 w = *(const float4*)&wS[kk][c4];
            float av[4] = {a.x, a.y, a.z, a.w};
            float wv[4] = {w.x, w.y, w.z, w.w};
            #pragma unroll
            for (int i2 = 0; i2 < 4; ++i2)
                #pragma unroll
                for (int j = 0; j < 4; ++j)
                    acc[i2][j] += av[i2] * wv[j];
        }
        __syncthreads();
    }
    // epilogue: add bias, write h (in place over agg), accumulate BN sums
    float bv[4];
    #pragma unroll
    for (int j = 0; j < 4; ++j) bv[j] = br[c4 + j];
    float colp[4] = {}, sqp[4] = {};
    #pragma unroll
    for (int i = 0; i < 4; ++i) {
        int row = row0 + r4 + i;
        bool valid = row < NN;
        #pragma unroll
        for (int j = 0; j < 4; ++j) {
            float v = acc[i][j] + bv[j];
            if (valid) {
                ws[AGG + (size_t)row*DD + c4 + j] = v;
                colp[j] += v;
                sqp[j]  += v * v;
            }
        }
    }
    #pragma unroll
    for (int j = 0; j < 4; ++j) red[rg][c4 + j] = colp[j];
    __syncthreads();
    if (tid < 128) {
        float s = 0.f;
        #pragma unroll
        for (int g = 0; g < 8; ++g) s += red[g][tid];
        atomicAdd(&ws[CSUM + tid], s);
    }
    __syncthreads();
    #pragma unroll
    for (int j = 0; j < 4; ++j) red[rg][c4 + j] = sqp[j];
    __syncthreads();
    if (tid < 128) {
        float s = 0.f;
        #pragma unroll
        for (int g = 0; g < 8; ++g) s += red[g][tid];
        atomicAdd(&ws[CSQ + tid], s);
    }
}

// ---- BN affine folding: scale = gamma*rsqrt(var+eps), shift = beta - scale*mean
__global__ void k_stats(const float* __restrict__ gamma, const float* __restrict__ beta,
                        float* __restrict__ ws) {
    int o = threadIdx.x;
    float mean = ws[CSUM + o] * (1.0f / NN);
    float var  = ws[CSQ + o] * (1.0f / NN) - mean * mean;
    float inv  = rsqrtf(var + EPS);
    float sc   = gamma[o] * inv;
    ws[SCL + o] = sc;
    ws[SHF + o] = beta[o] - sc * mean;
}

// ---- normalize + relu + segment-max (batch sorted -> running max, flush on change)
__global__ void k_pool(const int* __restrict__ batch, float* __restrict__ ws) {
    int d  = threadIdx.x;
    int n0 = blockIdx.x * 64;
    int n1 = n0 + 64; if (n1 > NN) n1 = NN;
    float sc = ws[SCL + d], sh = ws[SHF + d];
    int cur = -1;
    float m = 0.f;   // relu(max(S)) == max over relu'd values with identity 0
    for (int n = n0; n < n1; ++n) {
        int g = batch[n];                  // wave-uniform
        if (g != cur) {
            if (cur >= 0)
                atomicMax((int*)&ws[POOL + (size_t)cur*DD + d], __float_as_int(m));
            cur = g; m = 0.f;
        }
        float v = ws[AGG + (size_t)n*DD + d] * sc + sh;
        m = fmaxf(m, fmaxf(v, 0.f));
    }
    if (cur >= 0)
        atomicMax((int*)&ws[POOL + (size_t)cur*DD + d], __float_as_int(m));
}

// ---- classifier: out[g] = relu_pooled[g] @ Wc^T + bc
__global__ void k_cls(const float* __restrict__ Wc, const float* __restrict__ bc,
                      const float* __restrict__ ws, float* __restrict__ out) {
    __shared__ float pS[128];
    int g = blockIdx.x, t = threadIdx.x;
    pS[t] = ws[POOL + (size_t)g*DD + t];
    __syncthreads();
    if (t < NO) {
        float acc = bc[t];
        #pragma unroll 8
        for (int k = 0; k < DD; ++k) acc += pS[k] * Wc[t*DD + k];
        out[g*NO + t] = acc;
    }
}

extern "C" void kernel_launch(void* const* d_in, const int* in_sizes, int n_in,
                              void* d_out, int out_size, void* d_ws, size_t ws_size,
                              hipStream_t stream) {
    const float* x     = (const float*)d_in[0];
    const int*   ei    = (const int*)  d_in[1];
    const int*   batch = (const int*)  d_in[2];
    // d_in[3] is i==0 -> no-dropout branch; unused
    const float* Wrel  = (const float*)d_in[4];
    const float* brel  = (const float*)d_in[5];
    const float* Wroot = (const float*)d_in[6];
    const float* gamma = (const float*)d_in[7];
    const float* beta  = (const float*)d_in[8];
    const float* Wc    = (const float*)d_in[9];
    const float* bc    = (const float*)d_in[10];
    float* ws  = (float*)d_ws;
    int*   wi  = (int*)d_ws;
    float* out = (float*)d_out;

    // zero: BN sums + pooled (floats, contiguous) and CNT histogram (ints)
    hipMemsetAsync(ws + CSUM, 0, (2*DD + (size_t)NG*DD) * sizeof(float), stream);
    hipMemsetAsync(wi + CNT, 0, NN * sizeof(int), stream);

    constexpr int NB = (NN + 255) / 256;   // 196 scan blocks
    k_fold  <<<DD, DD, 0, stream>>>(Wrel, brel, Wroot, ws);
    k_hist  <<<(NE + 255)/256, 256, 0, stream>>>(ei, wi);
    k_scan1 <<<NB, 256, 0, stream>>>(wi, wi + BSX);          // reuse BSX as temp bsum
    k_scan2 <<<1, 256, 0, stream>>>(wi, wi + BSX, NB);       // in-place -> exclusive
    k_scan3 <<<NB, 256, 0, stream>>>(wi);
    k_fill  <<<(NE + 255)/256, 256, 0, stream>>>(ei, wi);
    k_gather<<<(NN + 7)/8, 256, 0, stream>>>(x, wi, ws);
    k_gemm  <<<(NN + 31)/32, 256, 0, stream>>>(x, ws);
    k_stats <<<1, DD, 0, stream>>>(gamma, beta, ws);
    k_pool  <<<(NN + 63)/64, DD, 0, stream>>>(batch, ws);
    k_cls   <<<NG, DD, 0, stream>>>(Wc, bc, ws, out);
}

// Round 3
// 309.803 us; speedup vs baseline: 1.7008x; 1.0559x over previous
//
#include <hip/hip_runtime.h>

#define EPS 1e-5f

constexpr int NN = 50000, NE = 800000, DD = 128, NG = 512, NC = 5, NO = 96;

typedef __attribute__((ext_vector_type(8))) short bf16x8;   // 8 bf16 = 4 VGPRs
typedef __attribute__((ext_vector_type(4))) float f32x4;

// ---- workspace layout (float units) ----
constexpr size_t HB   = 0;                        // ushort[NN*128]: aggB in, h(bf16) out (in place)
constexpr size_t XB   = (size_t)NN * DD / 2;      // ushort[NN*128]: x in bf16
constexpr size_t WB   = XB + (size_t)NN * DD / 2; // ushort[128*256]: folded W, [col][k] k-major
constexpr size_t BRO  = WB + DD * 256 / 2;        // [DD] folded bias fp32
constexpr size_t SCL  = BRO + DD;                 // [DD]
constexpr size_t SHF  = SCL + DD;                 // [DD]
constexpr size_t CSUM = SHF + DD;                 // [DD]   -- zeroed each call
constexpr size_t CSQ  = CSUM + DD;                // [DD]
constexpr size_t POOL = CSQ + DD;                 // [NG*DD]
constexpr size_t F_END = POOL + (size_t)NG * DD;
// int section
constexpr size_t CNT  = F_END;                    // [NN] histogram (consumed by fill)
constexpr size_t ROFF = CNT + NN;                 // [NN+1]
constexpr size_t BSX  = ROFF + NN + 1;            // [256]
constexpr size_t CSR  = BSX + 256;                // [NE]

static __device__ __forceinline__ unsigned short f2b(float f) {   // fp32 -> bf16 RNE
    unsigned int u = __float_as_uint(f);
    return (unsigned short)((u + 0x7FFFu + ((u >> 16) & 1u)) >> 16);
}
static __device__ __forceinline__ float b2f(unsigned short h) {
    return __uint_as_float(((unsigned int)h) << 16);
}

// ---- fold 5 convs' weights into bf16 W [col(128)][k(256)], k-major; fp32 bias
__global__ void k_fold(const float* __restrict__ Wrel, const float* __restrict__ brel,
                       const float* __restrict__ Wroot, float* __restrict__ ws) {
    int o = threadIdx.x, k = blockIdx.x;
    float wr = 0.f, wt = 0.f;
    for (int c = 0; c < NC; ++c) {
        wr += Wrel [c*DD*DD + o*DD + k];
        wt += Wroot[c*DD*DD + o*DD + k];
    }
    unsigned short* wb = (unsigned short*)(ws + WB);
    wb[o*256 + k]       = f2b(wr);   // k<128  -> agg path
    wb[o*256 + 128 + k] = f2b(wt);   // k>=128 -> root path
    if (k == 0) {
        float b = 0.f;
        for (int c = 0; c < NC; ++c) b += brel[c*DD + o];
        ws[BRO + o] = b;
    }
}

// ---- x -> bf16
__global__ void k_xcast(const float* __restrict__ x, float* __restrict__ ws) {
    int i = blockIdx.x * 256 + threadIdx.x;          // group of 4 elems; grid exact
    float4 v = ((const float4*)x)[i];
    ushort4 o = {f2b(v.x), f2b(v.y), f2b(v.z), f2b(v.w)};
    ((ushort4*)(ws + XB))[i] = o;
}

// ---- CSR build: histogram of dst
__global__ void k_hist(const int* __restrict__ ei, int* __restrict__ wi) {
    int e = blockIdx.x * 256 + threadIdx.x;
    if (e < NE) atomicAdd(&wi[CNT + ei[NE + e]], 1);
}

__global__ void k_scan1(const int* __restrict__ wi, int* __restrict__ bsum) {
    __shared__ int s[256];
    int t = threadIdx.x, i = blockIdx.x * 256 + t;
    s[t] = (i < NN) ? wi[CNT + i] : 0;
    __syncthreads();
    for (int off = 128; off > 0; off >>= 1) {
        if (t < off) s[t] += s[t + off];
        __syncthreads();
    }
    if (t == 0) bsum[blockIdx.x] = s[0];
}

__global__ void k_scan2(int* __restrict__ wi, const int* __restrict__ bsum, int nb) {
    __shared__ int s[256];
    int t = threadIdx.x;
    int v = (t < nb) ? bsum[t] : 0;
    s[t] = v;
    __syncthreads();
    for (int off = 1; off < 256; off <<= 1) {
        int u = (t >= off) ? s[t - off] : 0;
        __syncthreads();
        s[t] += u;
        __syncthreads();
    }
    wi[BSX + t] = s[t] - v;
}

__global__ void k_scan3(int* __restrict__ wi) {
    __shared__ int s[256];
    int t = threadIdx.x, b = blockIdx.x, i = b * 256 + t;
    int v = (i < NN) ? wi[CNT + i] : 0;
    s[t] = v;
    __syncthreads();
    for (int off = 1; off < 256; off <<= 1) {
        int u = (t >= off) ? s[t - off] : 0;
        __syncthreads();
        s[t] += u;
        __syncthreads();
    }
    if (i < NN) wi[ROFF + i] = wi[BSX + b] + s[t] - v;
    if (b == 0 && t == 0) wi[ROFF + NN] = NE;
}

__global__ void k_fill(const int* __restrict__ ei, int* __restrict__ wi) {
    int e = blockIdx.x * 256 + threadIdx.x;
    if (e >= NE) return;
    int src = ei[e];
    int dst = ei[NE + e];
    int p = atomicSub(&wi[CNT + dst], 1) - 1;
    wi[CSR + wi[ROFF + dst] + p] = src;
}

// ---- gather-sum in fp32, store bf16 agg into HB
__global__ __launch_bounds__(256) void k_gather(const float* __restrict__ x,
                                                const int* __restrict__ wi,
                                                float* __restrict__ ws) {
    int tid  = threadIdx.x;
    int n    = blockIdx.x * 8 + (tid >> 5);
    int lane = tid & 31;
    int c4   = lane * 4;
    if (n >= NN) return;
    int e0 = wi[ROFF + n], e1 = wi[ROFF + n + 1];
    int cnt = e1 - e0;
    float4 acc = {0.f, 0.f, 0.f, 0.f};
    for (int base = 0; base < cnt; base += 32) {
        int myE = (base + lane < cnt) ? wi[CSR + e0 + base + lane] : 0;
        int m = cnt - base; if (m > 32) m = 32;
        for (int j = 0; j < m; ++j) {
            int s = __shfl(myE, j, 32);
            float4 v = *(const float4*)&x[(size_t)s * DD + c4];
            acc.x += v.x; acc.y += v.y; acc.z += v.z; acc.w += v.w;
        }
    }
    ushort4 o = {f2b(acc.x), f2b(acc.y), f2b(acc.z), f2b(acc.w)};
    *(ushort4*)&((unsigned short*)(ws + HB))[(size_t)n * DD + c4] = o;
}

// ---- MFMA GEMM: h = aggB @ Wr^T + xB @ Wt^T + br  (bf16 in, fp32 acc, bf16 h in place)
// wave w owns rows [blk*64 + w*16, +16) x all 128 cols; 64 mfma_16x16x32 per wave.
__global__ __launch_bounds__(256) void k_gemm(float* __restrict__ ws) {
    __shared__ float sSum[128], sSq[128];
    const unsigned short* hb = (const unsigned short*)(ws + HB);
    const unsigned short* xb = (const unsigned short*)(ws + XB);
    const unsigned short* wb = (const unsigned short*)(ws + WB);
    int tid  = threadIdx.x;
    if (tid < 128) { sSum[tid] = 0.f; sSq[tid] = 0.f; }
    __syncthreads();
    int wave = tid >> 6, lane = tid & 63;
    int quad = lane >> 4, l16 = lane & 15;
    int row0 = blockIdx.x * 64 + wave * 16;
    int arow = row0 + l16; if (arow > NN - 1) arow = NN - 1;   // clamp; masked below
    const unsigned short* aggRow = hb + (size_t)arow * DD;
    const unsigned short* xRow   = xb + (size_t)arow * DD;
    f32x4 acc[8] = {};
    #pragma unroll
    for (int kt = 0; kt < 8; ++kt) {
        int k0 = kt * 32;
        const unsigned short* Ap = (kt < 4) ? (aggRow + k0 + quad*8)
                                            : (xRow + (k0 - 128) + quad*8);
        bf16x8 a = *(const bf16x8*)Ap;
        #pragma unroll
        for (int nt = 0; nt < 8; ++nt) {
            // B[k][n] = W[n][k]; lane: n = nt*16+l16, k = k0 + quad*8 + j (contig in wb)
            bf16x8 b = *(const bf16x8*)(wb + (size_t)(nt*16 + l16)*256 + k0 + quad*8);
            acc[nt] = __builtin_amdgcn_mfma_f32_16x16x32_bf16(a, b, acc[nt], 0, 0, 0);
        }
    }
    // epilogue: C/D layout col = l16, row = quad*4 + reg
    unsigned short* hbo = (unsigned short*)(ws + HB);
    #pragma unroll
    for (int nt = 0; nt < 8; ++nt) {
        int col = nt * 16 + l16;
        float bias = ws[BRO + col];
        float cs = 0.f, cq = 0.f;
        #pragma unroll
        for (int r = 0; r < 4; ++r) {
            int row = row0 + quad * 4 + r;
            float v = acc[nt][r] + bias;
            if (row < NN) {
                hbo[(size_t)row * DD + col] = f2b(v);
                cs += v; cq += v * v;
            }
        }
        // reduce across quads (rows) -> per-column sums for this wave
        cs += __shfl_xor(cs, 16); cs += __shfl_xor(cs, 32);
        cq += __shfl_xor(cq, 16); cq += __shfl_xor(cq, 32);
        if (quad == 0) { atomicAdd(&sSum[col], cs); atomicAdd(&sSq[col], cq); }
    }
    __syncthreads();
    if (tid < 128) {
        atomicAdd(&ws[CSUM + tid], sSum[tid]);
        atomicAdd(&ws[CSQ  + tid], sSq[tid]);
    }
}

// ---- BN affine fold
__global__ void k_stats(const float* __restrict__ gamma, const float* __restrict__ beta,
                        float* __restrict__ ws) {
    int o = threadIdx.x;
    float mean = ws[CSUM + o] * (1.0f / NN);
    float var  = ws[CSQ + o] * (1.0f / NN) - mean * mean;
    float inv  = rsqrtf(var + EPS);
    float sc   = gamma[o] * inv;
    ws[SCL + o] = sc;
    ws[SHF + o] = beta[o] - sc * mean;
}

// ---- normalize + relu + segment-max (batch sorted -> running max per chunk)
__global__ void k_pool(const int* __restrict__ batch, float* __restrict__ ws) {
    int d  = threadIdx.x;
    int n0 = blockIdx.x * 64;
    int n1 = n0 + 64; if (n1 > NN) n1 = NN;
    const unsigned short* hb = (const unsigned short*)(ws + HB);
    float sc = ws[SCL + d], sh = ws[SHF + d];
    int cur = -1;
    float m = 0.f;
    for (int n = n0; n < n1; ++n) {
        int g = batch[n];                  // wave-uniform
        if (g != cur) {
            if (cur >= 0)
                atomicMax((int*)&ws[POOL + (size_t)cur*DD + d], __float_as_int(m));
            cur = g; m = 0.f;
        }
        float v = b2f(hb[(size_t)n*DD + d]) * sc + sh;
        m = fmaxf(m, fmaxf(v, 0.f));
    }
    if (cur >= 0)
        atomicMax((int*)&ws[POOL + (size_t)cur*DD + d], __float_as_int(m));
}

// ---- classifier
__global__ void k_cls(const float* __restrict__ Wc, const float* __restrict__ bc,
                      const float* __restrict__ ws, float* __restrict__ out) {
    __shared__ float pS[128];
    int g = blockIdx.x, t = threadIdx.x;
    pS[t] = ws[POOL + (size_t)g*DD + t];
    __syncthreads();
    if (t < NO) {
        float acc = bc[t];
        #pragma unroll 8
        for (int k = 0; k < DD; ++k) acc += pS[k] * Wc[t*DD + k];
        out[g*NO + t] = acc;
    }
}

extern "C" void kernel_launch(void* const* d_in, const int* in_sizes, int n_in,
                              void* d_out, int out_size, void* d_ws, size_t ws_size,
                              hipStream_t stream) {
    const float* x     = (const float*)d_in[0];
    const int*   ei    = (const int*)  d_in[1];
    const int*   batch = (const int*)  d_in[2];
    const float* Wrel  = (const float*)d_in[4];
    const float* brel  = (const float*)d_in[5];
    const float* Wroot = (const float*)d_in[6];
    const float* gamma = (const float*)d_in[7];
    const float* beta  = (const float*)d_in[8];
    const float* Wc    = (const float*)d_in[9];
    const float* bc    = (const float*)d_in[10];
    float* ws  = (float*)d_ws;
    int*   wi  = (int*)d_ws;
    float* out = (float*)d_out;

    // zero: CSUM+CSQ+POOL (contiguous floats) and CNT (ints)
    hipMemsetAsync(ws + CSUM, 0, (2*DD + (size_t)NG*DD) * sizeof(float), stream);
    hipMemsetAsync(wi + CNT, 0, NN * sizeof(int), stream);

    constexpr int NB = (NN + 255) / 256;
    k_xcast <<<NN*DD/4/256, 256, 0, stream>>>(x, ws);
    k_fold  <<<DD, DD, 0, stream>>>(Wrel, brel, Wroot, ws);
    k_hist  <<<(NE + 255)/256, 256, 0, stream>>>(ei, wi);
    k_scan1 <<<NB, 256, 0, stream>>>(wi, wi + BSX);
    k_scan2 <<<1, 256, 0, stream>>>(wi, wi + BSX, NB);
    k_scan3 <<<NB, 256, 0, stream>>>(wi);
    k_fill  <<<(NE + 255)/256, 256, 0, stream>>>(ei, wi);
    k_gather<<<(NN + 7)/8, 256, 0, stream>>>(x, wi, ws);
    k_gemm  <<<(NN + 63)/64, 256, 0, stream>>>(ws);
    k_stats <<<1, DD, 0, stream>>>(gamma, beta, ws);
    k_pool  <<<(NN + 63)/64, DD, 0, stream>>>(batch, ws);
    k_cls   <<<NG, DD, 0, stream>>>(Wc, bc, ws, out);
}

// Round 4
// 254.711 us; speedup vs baseline: 2.0687x; 1.2163x over previous
//
#include <hip/hip_runtime.h>

#define EPS 1e-5f

constexpr int NN = 50000, NE = 800000, DD = 128, NG = 512, NC = 5, NO = 96;

typedef __attribute__((ext_vector_type(8))) short bf16x8;   // 8 bf16 = 4 VGPRs
typedef __attribute__((ext_vector_type(4))) float f32x4;

// ---- workspace layout (float units) ----
constexpr size_t HB   = 0;                        // ushort[NN*128]: aggB in, h(bf16) out (in place)
constexpr size_t XB   = (size_t)NN * DD / 2;      // ushort[NN*128]: x in bf16
constexpr size_t WB   = XB + (size_t)NN * DD / 2; // ushort[128*256]: folded W, [col][k] k-major
constexpr size_t BRO  = WB + DD * 256 / 2;        // [DD] folded bias fp32
constexpr size_t SCL  = BRO + DD;                 // [DD]
constexpr size_t SHF  = SCL + DD;                 // [DD]
constexpr size_t CSUM = SHF + DD;                 // [DD]   -- zeroed each call
constexpr size_t CSQ  = CSUM + DD;                // [DD]
constexpr size_t POOL = CSQ + DD;                 // [NG*DD]
constexpr size_t F_END = POOL + (size_t)NG * DD;
// int section
constexpr size_t CNT  = F_END;                    // [NN] histogram
constexpr size_t ROFF = CNT + NN;                 // [NN+1]
constexpr size_t BSX  = ROFF + NN + 1;            // [256]
constexpr size_t CSR  = BSX + 256;                // [NE] src indices grouped by dst
constexpr size_t PERM = CSR + NE;                 // [NE] within-row rank per edge

static __device__ __forceinline__ unsigned short f2b(float f) {   // fp32 -> bf16 RNE
    unsigned int u = __float_as_uint(f);
    return (unsigned short)((u + 0x7FFFu + ((u >> 16) & 1u)) >> 16);
}
static __device__ __forceinline__ float b2f(unsigned short h) {
    return __uint_as_float(((unsigned int)h) << 16);
}

// ---- fold 5 convs' weights into bf16 W [col(128)][k(256)], k-major; fp32 bias
__global__ void k_fold(const float* __restrict__ Wrel, const float* __restrict__ brel,
                       const float* __restrict__ Wroot, float* __restrict__ ws) {
    int o = threadIdx.x, k = blockIdx.x;
    float wr = 0.f, wt = 0.f;
    for (int c = 0; c < NC; ++c) {
        wr += Wrel [c*DD*DD + o*DD + k];
        wt += Wroot[c*DD*DD + o*DD + k];
    }
    unsigned short* wb = (unsigned short*)(ws + WB);
    wb[o*256 + k]       = f2b(wr);   // k<128  -> agg path
    wb[o*256 + 128 + k] = f2b(wt);   // k>=128 -> root path
    if (k == 0) {
        float b = 0.f;
        for (int c = 0; c < NC; ++c) b += brel[c*DD + o];
        ws[BRO + o] = b;
    }
}

// ---- x -> bf16
__global__ void k_xcast(const float* __restrict__ x, float* __restrict__ ws) {
    int i = blockIdx.x * 256 + threadIdx.x;          // group of 4 elems; grid exact
    float4 v = ((const float4*)x)[i];
    ushort4 o = {f2b(v.x), f2b(v.y), f2b(v.z), f2b(v.w)};
    ((ushort4*)(ws + XB))[i] = o;
}

// ---- CSR build: histogram of dst; save each edge's within-row rank
__global__ void k_hist(const int* __restrict__ ei, int* __restrict__ wi) {
    int e = blockIdx.x * 256 + threadIdx.x;
    if (e < NE) wi[PERM + e] = atomicAdd(&wi[CNT + ei[NE + e]], 1);
}

__global__ void k_scan1(const int* __restrict__ wi, int* __restrict__ bsum) {
    __shared__ int s[256];
    int t = threadIdx.x, i = blockIdx.x * 256 + t;
    s[t] = (i < NN) ? wi[CNT + i] : 0;
    __syncthreads();
    for (int off = 128; off > 0; off >>= 1) {
        if (t < off) s[t] += s[t + off];
        __syncthreads();
    }
    if (t == 0) bsum[blockIdx.x] = s[0];
}

__global__ void k_scan2(int* __restrict__ wi, const int* __restrict__ bsum, int nb) {
    __shared__ int s[256];
    int t = threadIdx.x;
    int v = (t < nb) ? bsum[t] : 0;
    s[t] = v;
    __syncthreads();
    for (int off = 1; off < 256; off <<= 1) {
        int u = (t >= off) ? s[t - off] : 0;
        __syncthreads();
        s[t] += u;
        __syncthreads();
    }
    wi[BSX + t] = s[t] - v;
}

__global__ void k_scan3(int* __restrict__ wi) {
    __shared__ int s[256];
    int t = threadIdx.x, b = blockIdx.x, i = b * 256 + t;
    int v = (i < NN) ? wi[CNT + i] : 0;
    s[t] = v;
    __syncthreads();
    for (int off = 1; off < 256; off <<= 1) {
        int u = (t >= off) ? s[t - off] : 0;
        __syncthreads();
        s[t] += u;
        __syncthreads();
    }
    if (i < NN) wi[ROFF + i] = wi[BSX + b] + s[t] - v;
    if (b == 0 && t == 0) wi[ROFF + NN] = NE;
}

// ---- fill CSR: slot = roff[dst] + saved rank (no atomics)
__global__ void k_fill(const int* __restrict__ ei, int* __restrict__ wi) {
    int e = blockIdx.x * 256 + threadIdx.x;
    if (e >= NE) return;
    int src = ei[e];
    int dst = ei[NE + e];
    wi[CSR + wi[ROFF + dst] + wi[PERM + e]] = src;
}

// ---- gather-sum from bf16 x: agg[n] = sum_{e in row n} xb[csr[e]]  (fp32 acc, bf16 out)
// 16 lanes per node, each lane owns 8 contiguous cols (16B vector loads)
__global__ __launch_bounds__(256) void k_gather(const int* __restrict__ wi,
                                                float* __restrict__ ws) {
    const unsigned short* xb = (const unsigned short*)(ws + XB);
    unsigned short* hb = (unsigned short*)(ws + HB);
    int tid = threadIdx.x;
    int n   = blockIdx.x * 16 + (tid >> 4);
    int sub = tid & 15;
    int c8  = sub * 8;
    if (n >= NN) return;
    int e0 = wi[ROFF + n], e1 = wi[ROFF + n + 1];
    int cnt = e1 - e0;
    float acc[8] = {};
    for (int base = 0; base < cnt; base += 16) {
        int myE = (base + sub < cnt) ? wi[CSR + e0 + base + sub] : 0;  // coalesced 64B/group
        int m = cnt - base; if (m > 16) m = 16;
        for (int j = 0; j < m; ++j) {
            int s = __shfl(myE, j, 16);             // broadcast within 16-lane group
            bf16x8 v = *(const bf16x8*)&xb[(size_t)s * DD + c8];
            #pragma unroll
            for (int c = 0; c < 8; ++c) acc[c] += b2f((unsigned short)v[c]);
        }
    }
    ushort4 o0 = {f2b(acc[0]), f2b(acc[1]), f2b(acc[2]), f2b(acc[3])};
    ushort4 o1 = {f2b(acc[4]), f2b(acc[5]), f2b(acc[6]), f2b(acc[7])};
    ushort4* dst = (ushort4*)&hb[(size_t)n * DD + c8];
    dst[0] = o0; dst[1] = o1;
}

// ---- MFMA GEMM: h = aggB @ Wr^T + xB @ Wt^T + br  (bf16 in, fp32 acc, bf16 h in place)
__global__ __launch_bounds__(256) void k_gemm(float* __restrict__ ws) {
    __shared__ float sSum[128], sSq[128];
    const unsigned short* hb = (const unsigned short*)(ws + HB);
    const unsigned short* xb = (const unsigned short*)(ws + XB);
    const unsigned short* wb = (const unsigned short*)(ws + WB);
    int tid  = threadIdx.x;
    if (tid < 128) { sSum[tid] = 0.f; sSq[tid] = 0.f; }
    __syncthreads();
    int wave = tid >> 6, lane = tid & 63;
    int quad = lane >> 4, l16 = lane & 15;
    int row0 = blockIdx.x * 64 + wave * 16;
    int arow = row0 + l16; if (arow > NN - 1) arow = NN - 1;   // clamp; masked below
    const unsigned short* aggRow = hb + (size_t)arow * DD;
    const unsigned short* xRow   = xb + (size_t)arow * DD;
    f32x4 acc[8] = {};
    #pragma unroll
    for (int kt = 0; kt < 8; ++kt) {
        int k0 = kt * 32;
        const unsigned short* Ap = (kt < 4) ? (aggRow + k0 + quad*8)
                                            : (xRow + (k0 - 128) + quad*8);
        bf16x8 a = *(const bf16x8*)Ap;
        #pragma unroll
        for (int nt = 0; nt < 8; ++nt) {
            bf16x8 b = *(const bf16x8*)(wb + (size_t)(nt*16 + l16)*256 + k0 + quad*8);
            acc[nt] = __builtin_amdgcn_mfma_f32_16x16x32_bf16(a, b, acc[nt], 0, 0, 0);
        }
    }
    unsigned short* hbo = (unsigned short*)(ws + HB);
    #pragma unroll
    for (int nt = 0; nt < 8; ++nt) {
        int col = nt * 16 + l16;
        float bias = ws[BRO + col];
        float cs = 0.f, cq = 0.f;
        #pragma unroll
        for (int r = 0; r < 4; ++r) {
            int row = row0 + quad * 4 + r;
            float v = acc[nt][r] + bias;
            if (row < NN) {
                hbo[(size_t)row * DD + col] = f2b(v);
                cs += v; cq += v * v;
            }
        }
        cs += __shfl_xor(cs, 16); cs += __shfl_xor(cs, 32);
        cq += __shfl_xor(cq, 16); cq += __shfl_xor(cq, 32);
        if (quad == 0) { atomicAdd(&sSum[col], cs); atomicAdd(&sSq[col], cq); }
    }
    __syncthreads();
    if (tid < 128) {
        atomicAdd(&ws[CSUM + tid], sSum[tid]);
        atomicAdd(&ws[CSQ  + tid], sSq[tid]);
    }
}

// ---- BN affine fold
__global__ void k_stats(const float* __restrict__ gamma, const float* __restrict__ beta,
                        float* __restrict__ ws) {
    int o = threadIdx.x;
    float mean = ws[CSUM + o] * (1.0f / NN);
    float var  = ws[CSQ + o] * (1.0f / NN) - mean * mean;
    float inv  = rsqrtf(var + EPS);
    float sc   = gamma[o] * inv;
    ws[SCL + o] = sc;
    ws[SHF + o] = beta[o] - sc * mean;
}

// ---- normalize + relu + segment-max (batch sorted -> running max per chunk)
__global__ void k_pool(const int* __restrict__ batch, float* __restrict__ ws) {
    int d  = threadIdx.x;
    int n0 = blockIdx.x * 64;
    int n1 = n0 + 64; if (n1 > NN) n1 = NN;
    const unsigned short* hb = (const unsigned short*)(ws + HB);
    float sc = ws[SCL + d], sh = ws[SHF + d];
    int cur = -1;
    float m = 0.f;
    for (int n = n0; n < n1; ++n) {
        int g = batch[n];                  // wave-uniform
        if (g != cur) {
            if (cur >= 0)
                atomicMax((int*)&ws[POOL + (size_t)cur*DD + d], __float_as_int(m));
            cur = g; m = 0.f;
        }
        float v = b2f(hb[(size_t)n*DD + d]) * sc + sh;
        m = fmaxf(m, fmaxf(v, 0.f));
    }
    if (cur >= 0)
        atomicMax((int*)&ws[POOL + (size_t)cur*DD + d], __float_as_int(m));
}

// ---- classifier
__global__ void k_cls(const float* __restrict__ Wc, const float* __restrict__ bc,
                      const float* __restrict__ ws, float* __restrict__ out) {
    __shared__ float pS[128];
    int g = blockIdx.x, t = threadIdx.x;
    pS[t] = ws[POOL + (size_t)g*DD + t];
    __syncthreads();
    if (t < NO) {
        float acc = bc[t];
        #pragma unroll 8
        for (int k = 0; k < DD; ++k) acc += pS[k] * Wc[t*DD + k];
        out[g*NO + t] = acc;
    }
}

extern "C" void kernel_launch(void* const* d_in, const int* in_sizes, int n_in,
                              void* d_out, int out_size, void* d_ws, size_t ws_size,
                              hipStream_t stream) {
    const float* x     = (const float*)d_in[0];
    const int*   ei    = (const int*)  d_in[1];
    const int*   batch = (const int*)  d_in[2];
    const float* Wrel  = (const float*)d_in[4];
    const float* brel  = (const float*)d_in[5];
    const float* Wroot = (const float*)d_in[6];
    const float* gamma = (const float*)d_in[7];
    const float* beta  = (const float*)d_in[8];
    const float* Wc    = (const float*)d_in[9];
    const float* bc    = (const float*)d_in[10];
    float* ws  = (float*)d_ws;
    int*   wi  = (int*)d_ws;
    float* out = (float*)d_out;

    // zero: CSUM+CSQ+POOL (contiguous floats) and CNT (ints)
    hipMemsetAsync(ws + CSUM, 0, (2*DD + (size_t)NG*DD) * sizeof(float), stream);
    hipMemsetAsync(wi + CNT, 0, NN * sizeof(int), stream);

    constexpr int NB = (NN + 255) / 256;
    k_xcast <<<NN*DD/4/256, 256, 0, stream>>>(x, ws);
    k_fold  <<<DD, DD, 0, stream>>>(Wrel, brel, Wroot, ws);
    k_hist  <<<(NE + 255)/256, 256, 0, stream>>>(ei, wi);
    k_scan1 <<<NB, 256, 0, stream>>>(wi, wi + BSX);
    k_scan2 <<<1, 256, 0, stream>>>(wi, wi + BSX, NB);
    k_scan3 <<<NB, 256, 0, stream>>>(wi);
    k_fill  <<<(NE + 255)/256, 256, 0, stream>>>(ei, wi);
    k_gather<<<(NN + 15)/16, 256, 0, stream>>>(wi, ws);
    k_gemm  <<<(NN + 63)/64, 256, 0, stream>>>(ws);
    k_stats <<<1, DD, 0, stream>>>(gamma, beta, ws);
    k_pool  <<<(NN + 63)/64, DD, 0, stream>>>(batch, ws);
    k_cls   <<<NG, DD, 0, stream>>>(Wc, bc, ws, out);
}

// Round 5
// 236.994 us; speedup vs baseline: 2.2234x; 1.0748x over previous
//
#include <hip/hip_runtime.h>

#define EPS 1e-5f

constexpr int NN = 50000, NE = 800000, DD = 128, NG = 512, NC = 5, NO = 96;

typedef __attribute__((ext_vector_type(8))) short bf16x8;   // 8 bf16 = 4 VGPRs
typedef __attribute__((ext_vector_type(4))) float f32x4;

// ---- workspace layout (float units) ----
constexpr size_t HB   = 0;                        // ushort[NN*128]: aggB in, h(bf16) out (in place)
constexpr size_t XB   = (size_t)NN * DD / 2;      // ushort[NN*128]: x in bf16
constexpr size_t WB   = XB + (size_t)NN * DD / 2; // ushort[128*256]: folded W, [col][k] k-major
constexpr size_t BRO  = WB + DD * 256 / 2;        // [DD] folded bias fp32
constexpr size_t SCL  = BRO + DD;                 // [DD]
constexpr size_t SHF  = SCL + DD;                 // [DD]
constexpr size_t CSUM = SHF + DD;                 // [DD]   -- zeroed each call
constexpr size_t CSQ  = CSUM + DD;                // [DD]
constexpr size_t POOL = CSQ + DD;                 // [NG*DD]
constexpr size_t F_END = POOL + (size_t)NG * DD;
// int section
constexpr size_t CNT  = F_END;                    // [NN] histogram
constexpr size_t ROFF = CNT + NN;                 // [NN+1]
constexpr size_t BSX  = ROFF + NN + 1;            // [256]
constexpr size_t CSR  = BSX + 256;                // [NE] src indices grouped by dst
constexpr size_t PERM = CSR + NE;                 // [NE] within-row rank per edge

static __device__ __forceinline__ unsigned short f2b(float f) {   // fp32 -> bf16 RNE
    unsigned int u = __float_as_uint(f);
    return (unsigned short)((u + 0x7FFFu + ((u >> 16) & 1u)) >> 16);
}
static __device__ __forceinline__ float b2f(unsigned short h) {
    return __uint_as_float(((unsigned int)h) << 16);
}

// ---- fold 5 convs' weights into bf16 W [col(128)][k(256)], k-major; fp32 bias
__global__ void k_fold(const float* __restrict__ Wrel, const float* __restrict__ brel,
                       const float* __restrict__ Wroot, float* __restrict__ ws) {
    int o = threadIdx.x, k = blockIdx.x;
    float wr = 0.f, wt = 0.f;
    for (int c = 0; c < NC; ++c) {
        wr += Wrel [c*DD*DD + o*DD + k];
        wt += Wroot[c*DD*DD + o*DD + k];
    }
    unsigned short* wb = (unsigned short*)(ws + WB);
    wb[o*256 + k]       = f2b(wr);   // k<128  -> agg path
    wb[o*256 + 128 + k] = f2b(wt);   // k>=128 -> root path
    if (k == 0) {
        float b = 0.f;
        for (int c = 0; c < NC; ++c) b += brel[c*DD + o];
        ws[BRO + o] = b;
    }
}

// ---- x -> bf16
__global__ void k_xcast(const float* __restrict__ x, float* __restrict__ ws) {
    int i = blockIdx.x * 256 + threadIdx.x;          // group of 4 elems; grid exact
    float4 v = ((const float4*)x)[i];
    ushort4 o = {f2b(v.x), f2b(v.y), f2b(v.z), f2b(v.w)};
    ((ushort4*)(ws + XB))[i] = o;
}

// ---- CSR build: histogram of dst; save each edge's within-row rank
__global__ void k_hist(const int* __restrict__ ei, int* __restrict__ wi) {
    int e = blockIdx.x * 256 + threadIdx.x;
    if (e < NE) wi[PERM + e] = atomicAdd(&wi[CNT + ei[NE + e]], 1);
}

__global__ void k_scan1(const int* __restrict__ wi, int* __restrict__ bsum) {
    __shared__ int s[256];
    int t = threadIdx.x, i = blockIdx.x * 256 + t;
    s[t] = (i < NN) ? wi[CNT + i] : 0;
    __syncthreads();
    for (int off = 128; off > 0; off >>= 1) {
        if (t < off) s[t] += s[t + off];
        __syncthreads();
    }
    if (t == 0) bsum[blockIdx.x] = s[0];
}

__global__ void k_scan2(int* __restrict__ wi, const int* __restrict__ bsum, int nb) {
    __shared__ int s[256];
    int t = threadIdx.x;
    int v = (t < nb) ? bsum[t] : 0;
    s[t] = v;
    __syncthreads();
    for (int off = 1; off < 256; off <<= 1) {
        int u = (t >= off) ? s[t - off] : 0;
        __syncthreads();
        s[t] += u;
        __syncthreads();
    }
    wi[BSX + t] = s[t] - v;
}

__global__ void k_scan3(int* __restrict__ wi) {
    __shared__ int s[256];
    int t = threadIdx.x, b = blockIdx.x, i = b * 256 + t;
    int v = (i < NN) ? wi[CNT + i] : 0;
    s[t] = v;
    __syncthreads();
    for (int off = 1; off < 256; off <<= 1) {
        int u = (t >= off) ? s[t - off] : 0;
        __syncthreads();
        s[t] += u;
        __syncthreads();
    }
    if (i < NN) wi[ROFF + i] = wi[BSX + b] + s[t] - v;
    if (b == 0 && t == 0) wi[ROFF + NN] = NE;
}

// ---- fill CSR: slot = roff[dst] + saved rank (no atomics)
__global__ void k_fill(const int* __restrict__ ei, int* __restrict__ wi) {
    int e = blockIdx.x * 256 + threadIdx.x;
    if (e >= NE) return;
    int src = ei[e];
    int dst = ei[NE + e];
    wi[CSR + wi[ROFF + dst] + wi[PERM + e]] = src;
}

// ---- gather-sum from bf16 x: agg[n] = sum_{e in row n} xb[csr[e]]  (fp32 acc, bf16 out)
__global__ __launch_bounds__(256) void k_gather(const int* __restrict__ wi,
                                                float* __restrict__ ws) {
    const unsigned short* xb = (const unsigned short*)(ws + XB);
    unsigned short* hb = (unsigned short*)(ws + HB);
    int tid = threadIdx.x;
    int n   = blockIdx.x * 16 + (tid >> 4);
    int sub = tid & 15;
    int c8  = sub * 8;
    if (n >= NN) return;
    int e0 = wi[ROFF + n], e1 = wi[ROFF + n + 1];
    int cnt = e1 - e0;
    float acc[8] = {};
    for (int base = 0; base < cnt; base += 16) {
        int myE = (base + sub < cnt) ? wi[CSR + e0 + base + sub] : 0;  // coalesced 64B/group
        int m = cnt - base; if (m > 16) m = 16;
        for (int j = 0; j < m; ++j) {
            int s = __shfl(myE, j, 16);             // broadcast within 16-lane group
            bf16x8 v = *(const bf16x8*)&xb[(size_t)s * DD + c8];
            #pragma unroll
            for (int c = 0; c < 8; ++c) acc[c] += b2f((unsigned short)v[c]);
        }
    }
    ushort4 o0 = {f2b(acc[0]), f2b(acc[1]), f2b(acc[2]), f2b(acc[3])};
    ushort4 o1 = {f2b(acc[4]), f2b(acc[5]), f2b(acc[6]), f2b(acc[7])};
    ushort4* dst = (ushort4*)&hb[(size_t)n * DD + c8];
    dst[0] = o0; dst[1] = o1;
}

// ---- MFMA GEMM, register-resident B: h = aggB @ Wr^T + xB @ Wt^T + br
// Block = 4 waves: wave = (rg<1>, ch<1>). Wave owns 64 cols (ch) x 64 rows (rg, 4 chunks
// of 16). B half (64 cols x 256 k) lives in 128 VGPRs, loaded once. Per-chunk
// __syncthreads orders A reads (full 128-col rows) before in-place h writes (col half).
__global__ __launch_bounds__(256) void k_gemm(float* __restrict__ ws) {
    __shared__ float sSum[128], sSq[128];
    const unsigned short* hb = (const unsigned short*)(ws + HB);
    const unsigned short* xb = (const unsigned short*)(ws + XB);
    const unsigned short* wb = (const unsigned short*)(ws + WB);
    unsigned short* hbo = (unsigned short*)(ws + HB);
    int tid  = threadIdx.x;
    if (tid < 128) { sSum[tid] = 0.f; sSq[tid] = 0.f; }
    int wave = tid >> 6, lane = tid & 63;
    int ch = wave & 1, rg = wave >> 1;
    int quad = lane >> 4, l16 = lane & 15;
    // load B half: 4 nt x 8 kt fragments (independent 16B loads, one-time cost)
    bf16x8 bf[4][8];
    #pragma unroll
    for (int nt = 0; nt < 4; ++nt)
        #pragma unroll
        for (int kt = 0; kt < 8; ++kt)
            bf[nt][kt] = *(const bf16x8*)(wb + (size_t)(ch*64 + nt*16 + l16)*256 + kt*32 + quad*8);
    float bias[4], csum[4] = {}, csq[4] = {};
    #pragma unroll
    for (int nt = 0; nt < 4; ++nt) bias[nt] = ws[BRO + ch*64 + nt*16 + l16];
    #pragma unroll
    for (int c = 0; c < 4; ++c) {
        int row0 = blockIdx.x * 128 + rg * 64 + c * 16;
        int arow = row0 + l16; if (arow > NN - 1) arow = NN - 1;   // clamp; masked below
        const unsigned short* aggRow = hb + (size_t)arow * DD;
        const unsigned short* xRow   = xb + (size_t)arow * DD;
        bf16x8 af[8];
        #pragma unroll
        for (int kt = 0; kt < 8; ++kt)
            af[kt] = *(const bf16x8*)((kt < 4 ? aggRow + kt*32 : xRow + kt*32 - 128) + quad*8);
        __syncthreads();   // all A reads (incl. other col-half wave) complete before h writes
        f32x4 acc[4] = {};
        #pragma unroll
        for (int kt = 0; kt < 8; ++kt)
            #pragma unroll
            for (int nt = 0; nt < 4; ++nt)
                acc[nt] = __builtin_amdgcn_mfma_f32_16x16x32_bf16(af[kt], bf[nt][kt], acc[nt], 0, 0, 0);
        // epilogue: C/D layout col=l16, row=quad*4+reg; write col half, in place
        #pragma unroll
        for (int nt = 0; nt < 4; ++nt) {
            int col = ch*64 + nt*16 + l16;
            #pragma unroll
            for (int r = 0; r < 4; ++r) {
                int row = row0 + quad*4 + r;
                float v = acc[nt][r] + bias[nt];
                if (row < NN) {
                    hbo[(size_t)row * DD + col] = f2b(v);
                    csum[nt] += v; csq[nt] += v * v;
                }
            }
        }
    }
    // BN sums: reduce rows (quads) -> col sums, accumulate in LDS then global
    #pragma unroll
    for (int nt = 0; nt < 4; ++nt) {
        int col = ch*64 + nt*16 + l16;
        float cs = csum[nt], cq = csq[nt];
        cs += __shfl_xor(cs, 16); cs += __shfl_xor(cs, 32);
        cq += __shfl_xor(cq, 16); cq += __shfl_xor(cq, 32);
        if (quad == 0) { atomicAdd(&sSum[col], cs); atomicAdd(&sSq[col], cq); }
    }
    __syncthreads();
    if (tid < 128) {
        atomicAdd(&ws[CSUM + tid], sSum[tid]);
        atomicAdd(&ws[CSQ  + tid], sSq[tid]);
    }
}

// ---- BN affine fold
__global__ void k_stats(const float* __restrict__ gamma, const float* __restrict__ beta,
                        float* __restrict__ ws) {
    int o = threadIdx.x;
    float mean = ws[CSUM + o] * (1.0f / NN);
    float var  = ws[CSQ + o] * (1.0f / NN) - mean * mean;
    float inv  = rsqrtf(var + EPS);
    float sc   = gamma[o] * inv;
    ws[SCL + o] = sc;
    ws[SHF + o] = beta[o] - sc * mean;
}

// ---- normalize + relu + segment-max (batch sorted -> running max per chunk)
__global__ void k_pool(const int* __restrict__ batch, float* __restrict__ ws) {
    int d  = threadIdx.x;
    int n0 = blockIdx.x * 64;
    int n1 = n0 + 64; if (n1 > NN) n1 = NN;
    const unsigned short* hb = (const unsigned short*)(ws + HB);
    float sc = ws[SCL + d], sh = ws[SHF + d];
    int cur = -1;
    float m = 0.f;
    for (int n = n0; n < n1; ++n) {
        int g = batch[n];                  // wave-uniform
        if (g != cur) {
            if (cur >= 0)
                atomicMax((int*)&ws[POOL + (size_t)cur*DD + d], __float_as_int(m));
            cur = g; m = 0.f;
        }
        float v = b2f(hb[(size_t)n*DD + d]) * sc + sh;
        m = fmaxf(m, fmaxf(v, 0.f));
    }
    if (cur >= 0)
        atomicMax((int*)&ws[POOL + (size_t)cur*DD + d], __float_as_int(m));
}

// ---- classifier
__global__ void k_cls(const float* __restrict__ Wc, const float* __restrict__ bc,
                      const float* __restrict__ ws, float* __restrict__ out) {
    __shared__ float pS[128];
    int g = blockIdx.x, t = threadIdx.x;
    pS[t] = ws[POOL + (size_t)g*DD + t];
    __syncthreads();
    if (t < NO) {
        float acc = bc[t];
        #pragma unroll 8
        for (int k = 0; k < DD; ++k) acc += pS[k] * Wc[t*DD + k];
        out[g*NO + t] = acc;
    }
}

extern "C" void kernel_launch(void* const* d_in, const int* in_sizes, int n_in,
                              void* d_out, int out_size, void* d_ws, size_t ws_size,
                              hipStream_t stream) {
    const float* x     = (const float*)d_in[0];
    const int*   ei    = (const int*)  d_in[1];
    const int*   batch = (const int*)  d_in[2];
    const float* Wrel  = (const float*)d_in[4];
    const float* brel  = (const float*)d_in[5];
    const float* Wroot = (const float*)d_in[6];
    const float* gamma = (const float*)d_in[7];
    const float* beta  = (const float*)d_in[8];
    const float* Wc    = (const float*)d_in[9];
    const float* bc    = (const float*)d_in[10];
    float* ws  = (float*)d_ws;
    int*   wi  = (int*)d_ws;
    float* out = (float*)d_out;

    // zero: CSUM+CSQ+POOL (contiguous floats) and CNT (ints)
    hipMemsetAsync(ws + CSUM, 0, (2*DD + (size_t)NG*DD) * sizeof(float), stream);
    hipMemsetAsync(wi + CNT, 0, NN * sizeof(int), stream);

    constexpr int NB = (NN + 255) / 256;
    k_xcast <<<NN*DD/4/256, 256, 0, stream>>>(x, ws);
    k_fold  <<<DD, DD, 0, stream>>>(Wrel, brel, Wroot, ws);
    k_hist  <<<(NE + 255)/256, 256, 0, stream>>>(ei, wi);
    k_scan1 <<<NB, 256, 0, stream>>>(wi, wi + BSX);
    k_scan2 <<<1, 256, 0, stream>>>(wi, wi + BSX, NB);
    k_scan3 <<<NB, 256, 0, stream>>>(wi);
    k_fill  <<<(NE + 255)/256, 256, 0, stream>>>(ei, wi);
    k_gather<<<(NN + 15)/16, 256, 0, stream>>>(wi, ws);
    k_gemm  <<<(NN + 127)/128, 256, 0, stream>>>(ws);
    k_stats <<<1, DD, 0, stream>>>(gamma, beta, ws);
    k_pool  <<<(NN + 63)/64, DD, 0, stream>>>(batch, ws);
    k_cls   <<<NG, DD, 0, stream>>>(Wc, bc, ws, out);
}

// Round 6
// 231.132 us; speedup vs baseline: 2.2797x; 1.0254x over previous
//
#include <hip/hip_runtime.h>

#define EPS 1e-5f

constexpr int NN = 50000, NE = 800000, DD = 128, NG = 512, NC = 5, NO = 96;

typedef __attribute__((ext_vector_type(8))) short bf16x8;   // 8 bf16 = 4 VGPRs
typedef __attribute__((ext_vector_type(4))) float f32x4;

// ---- workspace layout (4-byte units) ----
constexpr size_t HB   = 0;                        // ushort[NN*128]: aggB in, h(bf16) out (in place)
constexpr size_t XB   = (size_t)NN * DD / 2;      // ushort[NN*128]: x in bf16
constexpr size_t WB   = XB + (size_t)NN * DD / 2; // ushort[128*256]: folded W, [col][k] k-major
constexpr size_t BRO  = WB + DD * 256 / 2;        // [DD] folded bias fp32
// ---- contiguous zero region: CSUM..CTR (one memset) ----
constexpr size_t CSUM = BRO + DD;                 // [DD]
constexpr size_t CSQ  = CSUM + DD;                // [DD]
constexpr size_t POOL = CSQ + DD;                 // [NG*DD]
constexpr size_t CNT  = POOL + (size_t)NG * DD;   // [NN] histogram (int)
constexpr size_t CTR  = CNT + NN;                 // [1] scan completion counter
constexpr size_t ZEND = CTR + 1;
// ---- not zeroed ----
constexpr size_t ROFF = ZEND;                     // [NN+1] block-LOCAL exclusive offsets
constexpr size_t BSUM = ROFF + NN + 1;            // [256] per-block totals
constexpr size_t BSX  = BSUM + 256;               // [256] exclusive scan of block totals
constexpr size_t CSR  = BSX + 256;                // [NE] src indices grouped by dst
constexpr size_t PERM = CSR + NE;                 // [NE] within-row rank per edge

constexpr int XCAST_B = NN * DD / 4 / 256;        // 6250
constexpr int FOLD_B  = DD * DD / 256;            // 64
constexpr int HIST_B  = (NE + 255) / 256;         // 3125
constexpr int SCAN_B  = (NN + 255) / 256;         // 196

static __device__ __forceinline__ unsigned short f2b(float f) {   // fp32 -> bf16 RNE
    unsigned int u = __float_as_uint(f);
    return (unsigned short)((u + 0x7FFFu + ((u >> 16) & 1u)) >> 16);
}
static __device__ __forceinline__ float b2f(unsigned short h) {
    return __uint_as_float(((unsigned int)h) << 16);
}

// ---- fused prep: xcast (x->bf16) | fold weights | dst histogram + rank
__global__ __launch_bounds__(256) void k_prep(const float* __restrict__ x,
                                              const float* __restrict__ Wrel,
                                              const float* __restrict__ brel,
                                              const float* __restrict__ Wroot,
                                              const int* __restrict__ ei,
                                              float* __restrict__ ws, int* __restrict__ wi) {
    int b = blockIdx.x, t = threadIdx.x;
    if (b < XCAST_B) {
        int i = b * 256 + t;                       // float4 group; exact grid
        float4 v = ((const float4*)x)[i];
        ushort4 o = {f2b(v.x), f2b(v.y), f2b(v.z), f2b(v.w)};
        ((ushort4*)(ws + XB))[i] = o;
    } else if (b < XCAST_B + FOLD_B) {
        int idx = (b - XCAST_B) * 256 + t;         // 16384 (k,o) pairs
        int k = idx >> 7, o = idx & 127;
        float wr = 0.f, wt = 0.f;
        for (int c = 0; c < NC; ++c) {
            wr += Wrel [c*DD*DD + o*DD + k];
            wt += Wroot[c*DD*DD + o*DD + k];
        }
        unsigned short* wb = (unsigned short*)(ws + WB);
        wb[o*256 + k]       = f2b(wr);             // k<128  -> agg path
        wb[o*256 + 128 + k] = f2b(wt);             // k>=128 -> root path
        if (k == 0) {
            float bias = 0.f;
            for (int c = 0; c < NC; ++c) bias += brel[c*DD + o];
            ws[BRO + o] = bias;
        }
    } else {
        int e = (b - XCAST_B - FOLD_B) * 256 + t;  // exact: 3125*256 = 800000
        if (e < NE) wi[PERM + e] = atomicAdd(&wi[CNT + ei[NE + e]], 1);
    }
}

// ---- fused scan: per-block local exclusive scan of CNT -> ROFF(local) + block totals;
// last-arriving block scans the 196 totals -> BSX (exclusive). Consumers add BSX[i>>8].
__global__ __launch_bounds__(256) void k_scan12(int* __restrict__ wi) {
    __shared__ int s[256];
    __shared__ int lastFlag;
    int t = threadIdx.x, b = blockIdx.x, i = b * 256 + t;
    int v = (i < NN) ? wi[CNT + i] : 0;
    s[t] = v;
    __syncthreads();
    for (int off = 1; off < 256; off <<= 1) {
        int u = (t >= off) ? s[t - off] : 0;
        __syncthreads();
        s[t] += u;
        __syncthreads();
    }
    if (i < NN) wi[ROFF + i] = s[t] - v;               // block-local exclusive
    if (b == SCAN_B - 1 && t == 255) wi[ROFF + NN] = s[255];  // local total tail
    if (t == 0) {
        __hip_atomic_store(&wi[BSUM + b], s[255], __ATOMIC_RELAXED, __HIP_MEMORY_SCOPE_AGENT);
        int c = __hip_atomic_fetch_add(&wi[CTR], 1, __ATOMIC_ACQ_REL, __HIP_MEMORY_SCOPE_AGENT);
        lastFlag = (c == SCAN_B - 1);
    }
    __syncthreads();
    if (lastFlag) {                                    // block-uniform
        int v2 = (t < SCAN_B)
            ? __hip_atomic_load(&wi[BSUM + t], __ATOMIC_RELAXED, __HIP_MEMORY_SCOPE_AGENT) : 0;
        s[t] = v2;
        __syncthreads();
        for (int off = 1; off < 256; off <<= 1) {
            int u = (t >= off) ? s[t - off] : 0;
            __syncthreads();
            s[t] += u;
            __syncthreads();
        }
        wi[BSX + t] = s[t] - v2;                       // exclusive block offsets
    }
}

// ---- fill CSR: slot = local roff[dst] + block offset + saved rank (no atomics)
__global__ void k_fill(const int* __restrict__ ei, int* __restrict__ wi) {
    int e = blockIdx.x * 256 + threadIdx.x;
    if (e >= NE) return;
    int src = ei[e];
    int dst = ei[NE + e];
    wi[CSR + wi[ROFF + dst] + wi[BSX + (dst >> 8)] + wi[PERM + e]] = src;
}

// ---- gather-sum from bf16 x: agg[n] = sum_{e in row n} xb[csr[e]]  (fp32 acc, bf16 out)
// 16 lanes per node, each lane owns 8 contiguous cols (16B vector loads)
__global__ __launch_bounds__(256) void k_gather(const int* __restrict__ wi,
                                                float* __restrict__ ws) {
    const unsigned short* xb = (const unsigned short*)(ws + XB);
    unsigned short* hb = (unsigned short*)(ws + HB);
    int tid = threadIdx.x;
    int n   = blockIdx.x * 16 + (tid >> 4);
    int sub = tid & 15;
    int c8  = sub * 8;
    if (n >= NN) return;
    int e0 = wi[ROFF + n]     + wi[BSX + (n >> 8)];
    int e1 = wi[ROFF + n + 1] + wi[BSX + ((n + 1) >> 8)];
    int cnt = e1 - e0;
    float acc[8] = {};
    for (int base = 0; base < cnt; base += 16) {
        int myE = (base + sub < cnt) ? wi[CSR + e0 + base + sub] : 0;  // coalesced 64B/group
        int m = cnt - base; if (m > 16) m = 16;
        for (int j = 0; j < m; ++j) {
            int s = __shfl(myE, j, 16);             // broadcast within 16-lane group
            bf16x8 v = *(const bf16x8*)&xb[(size_t)s * DD + c8];
            #pragma unroll
            for (int c = 0; c < 8; ++c) acc[c] += b2f((unsigned short)v[c]);
        }
    }
    bf16x8 o;
    #pragma unroll
    for (int c = 0; c < 8; ++c) o[c] = (short)f2b(acc[c]);
    *(bf16x8*)&hb[(size_t)n * DD + c8] = o;         // one 16B store
}

// ---- MFMA GEMM, register-resident B: h = aggB @ Wr^T + xB @ Wt^T + br
// Block = 4 waves: wave = (rg<1>, ch<1>). Wave owns 64 cols (ch) x 64 rows (rg, 4 chunks
// of 16). B half (64 cols x 256 k) lives in 128 VGPRs, loaded once. Per-chunk
// __syncthreads orders A reads (full 128-col rows) before in-place h writes (col half).
__global__ __launch_bounds__(256) void k_gemm(float* __restrict__ ws) {
    __shared__ float sSum[128], sSq[128];
    const unsigned short* hb = (const unsigned short*)(ws + HB);
    const unsigned short* xb = (const unsigned short*)(ws + XB);
    const unsigned short* wb = (const unsigned short*)(ws + WB);
    unsigned short* hbo = (unsigned short*)(ws + HB);
    int tid  = threadIdx.x;
    if (tid < 128) { sSum[tid] = 0.f; sSq[tid] = 0.f; }
    int wave = tid >> 6, lane = tid & 63;
    int ch = wave & 1, rg = wave >> 1;
    int quad = lane >> 4, l16 = lane & 15;
    bf16x8 bf[4][8];
    #pragma unroll
    for (int nt = 0; nt < 4; ++nt)
        #pragma unroll
        for (int kt = 0; kt < 8; ++kt)
            bf[nt][kt] = *(const bf16x8*)(wb + (size_t)(ch*64 + nt*16 + l16)*256 + kt*32 + quad*8);
    float bias[4], csum[4] = {}, csq[4] = {};
    #pragma unroll
    for (int nt = 0; nt < 4; ++nt) bias[nt] = ws[BRO + ch*64 + nt*16 + l16];
    #pragma unroll
    for (int c = 0; c < 4; ++c) {
        int row0 = blockIdx.x * 128 + rg * 64 + c * 16;
        int arow = row0 + l16; if (arow > NN - 1) arow = NN - 1;   // clamp; masked below
        const unsigned short* aggRow = hb + (size_t)arow * DD;
        const unsigned short* xRow   = xb + (size_t)arow * DD;
        bf16x8 af[8];
        #pragma unroll
        for (int kt = 0; kt < 8; ++kt)
            af[kt] = *(const bf16x8*)((kt < 4 ? aggRow + kt*32 : xRow + kt*32 - 128) + quad*8);
        __syncthreads();   // all A reads (incl. other col-half wave) complete before h writes
        f32x4 acc[4] = {};
        #pragma unroll
        for (int kt = 0; kt < 8; ++kt)
            #pragma unroll
            for (int nt = 0; nt < 4; ++nt)
                acc[nt] = __builtin_amdgcn_mfma_f32_16x16x32_bf16(af[kt], bf[nt][kt], acc[nt], 0, 0, 0);
        #pragma unroll
        for (int nt = 0; nt < 4; ++nt) {
            int col = ch*64 + nt*16 + l16;
            #pragma unroll
            for (int r = 0; r < 4; ++r) {
                int row = row0 + quad*4 + r;
                float v = acc[nt][r] + bias[nt];
                if (row < NN) {
                    hbo[(size_t)row * DD + col] = f2b(v);
                    csum[nt] += v; csq[nt] += v * v;
                }
            }
        }
    }
    #pragma unroll
    for (int nt = 0; nt < 4; ++nt) {
        int col = ch*64 + nt*16 + l16;
        float cs = csum[nt], cq = csq[nt];
        cs += __shfl_xor(cs, 16); cs += __shfl_xor(cs, 32);
        cq += __shfl_xor(cq, 16); cq += __shfl_xor(cq, 32);
        if (quad == 0) { atomicAdd(&sSum[col], cs); atomicAdd(&sSq[col], cq); }
    }
    __syncthreads();
    if (tid < 128) {
        atomicAdd(&ws[CSUM + tid], sSum[tid]);
        atomicAdd(&ws[CSQ  + tid], sSq[tid]);
    }
}

// ---- pool with inlined BN stats: normalize + relu + segment-max; 64 threads, 2 cols/thread
__global__ __launch_bounds__(64) void k_pool(const int* __restrict__ batch,
                                             const float* __restrict__ gamma,
                                             const float* __restrict__ beta,
                                             float* __restrict__ ws) {
    int t  = threadIdx.x;
    int c0 = t * 2, c1 = c0 + 1;
    float mean0 = ws[CSUM + c0] * (1.0f / NN), mean1 = ws[CSUM + c1] * (1.0f / NN);
    float var0  = ws[CSQ + c0] * (1.0f / NN) - mean0 * mean0;
    float var1  = ws[CSQ + c1] * (1.0f / NN) - mean1 * mean1;
    float sc0 = gamma[c0] * rsqrtf(var0 + EPS), sc1 = gamma[c1] * rsqrtf(var1 + EPS);
    float sh0 = beta[c0] - sc0 * mean0,         sh1 = beta[c1] - sc1 * mean1;
    int n0 = blockIdx.x * 64;
    int n1 = n0 + 64; if (n1 > NN) n1 = NN;
    const unsigned int* hb32 = (const unsigned int*)ws;   // HB==0; 64 uints per row
    int cur = -1;
    float m0 = 0.f, m1 = 0.f;   // relu identity 0 matches POOL zero-init
    for (int n = n0; n < n1; ++n) {
        int g = batch[n];                  // wave-uniform
        if (g != cur) {
            if (cur >= 0) {
                atomicMax((int*)&ws[POOL + (size_t)cur*DD + c0], __float_as_int(m0));
                atomicMax((int*)&ws[POOL + (size_t)cur*DD + c1], __float_as_int(m1));
            }
            cur = g; m0 = 0.f; m1 = 0.f;
        }
        unsigned int u = hb32[(size_t)n * 64 + t];
        float v0 = __uint_as_float(u << 16)          * sc0 + sh0;
        float v1 = __uint_as_float(u & 0xFFFF0000u)  * sc1 + sh1;
        m0 = fmaxf(m0, fmaxf(v0, 0.f));
        m1 = fmaxf(m1, fmaxf(v1, 0.f));
    }
    if (cur >= 0) {
        atomicMax((int*)&ws[POOL + (size_t)cur*DD + c0], __float_as_int(m0));
        atomicMax((int*)&ws[POOL + (size_t)cur*DD + c1], __float_as_int(m1));
    }
}

// ---- classifier
__global__ void k_cls(const float* __restrict__ Wc, const float* __restrict__ bc,
                      const float* __restrict__ ws, float* __restrict__ out) {
    __shared__ float pS[128];
    int g = blockIdx.x, t = threadIdx.x;
    pS[t] = ws[POOL + (size_t)g*DD + t];
    __syncthreads();
    if (t < NO) {
        float acc = bc[t];
        #pragma unroll 8
        for (int k = 0; k < DD; ++k) acc += pS[k] * Wc[t*DD + k];
        out[g*NO + t] = acc;
    }
}

extern "C" void kernel_launch(void* const* d_in, const int* in_sizes, int n_in,
                              void* d_out, int out_size, void* d_ws, size_t ws_size,
                              hipStream_t stream) {
    const float* x     = (const float*)d_in[0];
    const int*   ei    = (const int*)  d_in[1];
    const int*   batch = (const int*)  d_in[2];
    const float* Wrel  = (const float*)d_in[4];
    const float* brel  = (const float*)d_in[5];
    const float* Wroot = (const float*)d_in[6];
    const float* gamma = (const float*)d_in[7];
    const float* beta  = (const float*)d_in[8];
    const float* Wc    = (const float*)d_in[9];
    const float* bc    = (const float*)d_in[10];
    float* ws  = (float*)d_ws;
    int*   wi  = (int*)d_ws;
    float* out = (float*)d_out;

    // one contiguous zero: CSUM, CSQ, POOL, CNT, CTR
    hipMemsetAsync(ws + CSUM, 0, (ZEND - CSUM) * sizeof(float), stream);

    k_prep  <<<XCAST_B + FOLD_B + HIST_B, 256, 0, stream>>>(x, Wrel, brel, Wroot, ei, ws, wi);
    k_scan12<<<SCAN_B, 256, 0, stream>>>(wi);
    k_fill  <<<HIST_B, 256, 0, stream>>>(ei, wi);
    k_gather<<<(NN + 15)/16, 256, 0, stream>>>(wi, ws);
    k_gemm  <<<(NN + 127)/128, 256, 0, stream>>>(ws);
    k_pool  <<<(NN + 63)/64, 64, 0, stream>>>(batch, gamma, beta, ws);
    k_cls   <<<NG, DD, 0, stream>>>(Wc, bc, ws, out);
}